// Round 9
// baseline (338.346 us; speedup 1.0000x reference)
//
#include <hip/hip_runtime.h>
#include <math.h>

// Problem constants (B=1, C=64, H=W=256, N=4096, T=0.1)
#define HW2     65536
#define NLOC    4096
#define NROW    8192
#define CDIM    64
#define TINV    10.0f
#define EXP10   22026.465794806718f   // exp(1/T)
#define NP      64                    // 128-row panels
#define NPAIR   2080                  // NP*(NP+1)/2
#define NBLK    1024                  // exactly 4 blocks/CU on 256 CUs

#if __has_builtin(__builtin_amdgcn_exp2f)
#define ASCALE  14.426950408889634f   // 10 * log2(e)
#define EXPFN(x) __builtin_amdgcn_exp2f(x)
#else
#define ASCALE  10.0f
#define EXPFN(x) __expf(x)
#endif

typedef __attribute__((ext_vector_type(8))) short bf16x8;
typedef __attribute__((ext_vector_type(4))) float f32x4;
typedef unsigned short u16;

__device__ __forceinline__ unsigned short f2bf(float f) {
  unsigned u = __builtin_bit_cast(unsigned, f);
  u += 0x7FFFu + ((u >> 16) & 1u);   // RNE
  return (unsigned short)(u >> 16);
}
__device__ __forceinline__ float bf2f(unsigned u16v) {
  unsigned u = u16v << 16;
  return __builtin_bit_cast(float, u);
}
// Scale a bf16x8 fragment by ASCALE with RNE re-round (bit-identical to the
// old Ga materialization).
__device__ __forceinline__ bf16x8 scale8(bf16x8 r) {
  bf16x8 o;
#pragma unroll
  for (int j = 0; j < 8; ++j)
    o[j] = (short)f2bf(bf2f((unsigned short)r[j]) * ASCALE);
  return o;
}

// ---------------------------------------------------------------------------
// Device-wide barrier (all NBLK blocks co-resident by construction).
// Release: per-wave vmcnt drain (__syncthreads) + __threadfence (L2 wb) +
// device-scope add.  Acquire: spin agent-scope load + __threadfence (L2 inv).
// Same ordering primitives R8's last-block reduce validated on this chip.
// ---------------------------------------------------------------------------
__device__ __forceinline__ void grid_barrier(unsigned* bar, int tid) {
  __syncthreads();
  if (tid == 0) {
    __threadfence();
    __hip_atomic_fetch_add(bar, 1u, __ATOMIC_RELAXED, __HIP_MEMORY_SCOPE_AGENT);
    while (__hip_atomic_load(bar, __ATOMIC_RELAXED, __HIP_MEMORY_SCOPE_AGENT) <
           (unsigned)NBLK)
      __builtin_amdgcn_s_sleep(2);
  }
  __syncthreads();
  __threadfence();
}

// ---------------------------------------------------------------------------
// Staging: one 64-row x 128B tile, XOR seg-swizzle (measured 0 conflicts).
// ---------------------------------------------------------------------------
__device__ __forceinline__ void stage_tile(u16* Bs, const u16* __restrict__ Gb,
                                           int jb, int buf, int tid, int wave,
                                           int srow, int ssl) {
#pragma unroll
  for (int r = 0; r < 2; ++r) {
    const u16* src = Gb + (size_t)(jb + r * 32 + srow) * CDIM + ssl * 8;
#if __has_builtin(__builtin_amdgcn_global_load_lds)
    u16* dst = Bs + buf * 4096 + r * 2048 + wave * 512;
    __builtin_amdgcn_global_load_lds(
        (const __attribute__((address_space(1))) unsigned int*)src,
        (__attribute__((address_space(3))) unsigned int*)dst, 16, 0, 0);
#else
    bf16x8 tmp = *reinterpret_cast<const bf16x8*>(src);
    *reinterpret_cast<bf16x8*>(Bs + buf * 4096 + r * 2048 + tid * 8) = tmp;
#endif
  }
}

// ---------------------------------------------------------------------------
// Mega-kernel: gather -> barrier -> triangular simsum -> barrier -> finalize.
// ---------------------------------------------------------------------------
__global__ __launch_bounds__(256, 4) void mega_kernel(
    const float* __restrict__ emb0, const float* __restrict__ emb1,
    const float* __restrict__ loc0, const float* __restrict__ loc1,
    u16* __restrict__ Gb, float* __restrict__ rowPart,
    float* __restrict__ partA, float* __restrict__ partB,
    unsigned* __restrict__ bars, float* __restrict__ out) {
  __shared__ union {
    struct { int ind[64]; u16 Gs[64][8]; } g;                 // phase 1
    struct { u16 Bs[2 * 64 * CDIM]; float colRed[4][128]; } s; // phase 2 (18KB)
    struct { float sA[256]; float sB[256]; int lastFlag; } f;  // phase 3
  } L;

  const int tid  = threadIdx.x;
  const int bid  = blockIdx.x;
  const int lane = tid & 63;
  const int wave = tid >> 6;

  // ===== Phase 1: channel-major gather (writes Gb only) =====
  {
    const int chunk = bid >> 3;       // 0..127 -> rows chunk*64..+64
    const int cgh   = bid & 7;        // channels cgh*8..+8
    const int eb    = chunk >> 6;
    const float* emb = eb ? emb1 : emb0;
    const float* loc = eb ? loc1 : loc0;

    if (tid < 64) {
      const int u = (chunk & 63) * 64 + tid;
      float2 lv = *reinterpret_cast<const float2*>(&loc[u * 2]);
      L.g.ind[tid] = (int)floorf(lv.x) * 256 + (int)floorf(lv.y);
    }
    __syncthreads();

    const int row = tid & 63;
    const int cq  = tid >> 6;         // 0..3
    const int pos = L.g.ind[row];
    // wave w: all lanes read channel cgh*8+w within ONE 256-KB slab
    float v0 = emb[(size_t)(cgh * 8 + cq) * HW2 + pos];
    float v1 = emb[(size_t)(cgh * 8 + cq + 4) * HW2 + pos];
    L.g.Gs[row][cq]     = f2bf(v0);
    L.g.Gs[row][cq + 4] = f2bf(v1);
    __syncthreads();

    if (tid < 64) {
      bf16x8 v = *reinterpret_cast<const bf16x8*>(&L.g.Gs[tid][0]);
      *reinterpret_cast<bf16x8*>(
          &Gb[(size_t)(chunk * 64 + tid) * CDIM + cgh * 8]) = v;
    }
  }

  grid_barrier(&bars[0], tid);

  // ===== Phase 2: triangular MFMA Gram + fused exp-rowsum =====
  const int lrow = lane & 15;
  const int kh   = lane >> 4;
  const int srow = tid >> 3;
  const int ssl  = (tid & 7) ^ (srow & 7);
  const int sp0  = ((kh ^ (lrow & 7)) << 3);
  const int sp1  = (((4 + kh) ^ (lrow & 7)) << 3);

  for (int tt = bid; tt < NPAIR; tt += NBLK) {
    // decode tt -> (p,q), p<=q
    int p = (int)((129.0f - sqrtf(16641.0f - 8.0f * (float)tt)) * 0.5f);
    if (p < 0) p = 0;
    if (p > NP - 1) p = NP - 1;
#pragma unroll
    for (int it = 0; it < 3; ++it) {
      if (p > 0 && (p * NP - p * (p - 1) / 2) > tt) --p;
      else if (((p + 1) * NP - (p + 1) * p / 2) <= tt) ++p;
    }
    const int q  = p + (tt - (p * NP - p * (p - 1) / 2));
    const int p0 = p * 128, q0 = q * 128;
    const int i0 = p0 + wave * 32;

    // A fragments from Gb, scaled in-register (bit-identical to old Ga).
    const bf16x8* arowA =
        reinterpret_cast<const bf16x8*>(Gb + (size_t)(i0 + lrow) * CDIM + kh * 8);
    const bf16x8* arowB = reinterpret_cast<const bf16x8*>(
        Gb + (size_t)(i0 + 16 + lrow) * CDIM + kh * 8);
    bf16x8 aA0 = scale8(arowA[0]), aA1 = scale8(arowA[4]);
    bf16x8 aB0 = scale8(arowB[0]), aB1 = scale8(arowB[4]);

    stage_tile(L.s.Bs, Gb, q0,      0, tid, wave, srow, ssl);
    stage_tile(L.s.Bs, Gb, q0 + 64, 1, tid, wave, srow, ssl);
    __syncthreads();

    float accA[4][4], accB[4][4];
#pragma unroll
    for (int nf = 0; nf < 4; ++nf)
#pragma unroll
      for (int r = 0; r < 4; ++r) { accA[nf][r] = 0.f; accB[nf][r] = 0.f; }
    float colAcc[2][4];

#pragma unroll
    for (int t = 0; t < 2; ++t) {
      const u16* bs = L.s.Bs + t * 4096;
#pragma unroll
      for (int nf = 0; nf < 4; ++nf) {
        const int rb = (nf * 16 + lrow) * CDIM;
        bf16x8 b0 = *reinterpret_cast<const bf16x8*>(bs + rb + sp0);
        bf16x8 b1 = *reinterpret_cast<const bf16x8*>(bs + rb + sp1);
        f32x4 z = {0.f, 0.f, 0.f, 0.f};
        f32x4 tA = __builtin_amdgcn_mfma_f32_16x16x32_bf16(aA0, b0, z, 0, 0, 0);
        tA = __builtin_amdgcn_mfma_f32_16x16x32_bf16(aA1, b1, tA, 0, 0, 0);
        f32x4 tB = __builtin_amdgcn_mfma_f32_16x16x32_bf16(aB0, b0, z, 0, 0, 0);
        tB = __builtin_amdgcn_mfma_f32_16x16x32_bf16(aB1, b1, tB, 0, 0, 0);
        float cp = 0.f;
#pragma unroll
        for (int r = 0; r < 4; ++r) {
          float eA = EXPFN(tA[r]);
          float eB = EXPFN(tB[r]);
          accA[nf][r] += eA;
          accB[nf][r] += eB;
          cp += eA + eB;
        }
        colAcc[t][nf] = cp;
      }
    }

    // Row-sums -> rowPart[p-rows][q]
#pragma unroll
    for (int r = 0; r < 4; ++r) {
      float vA = (accA[0][r] + accA[1][r]) + (accA[2][r] + accA[3][r]);
      float vB = (accB[0][r] + accB[1][r]) + (accB[2][r] + accB[3][r]);
      vA += __shfl_xor(vA, 1, 16);
      vA += __shfl_xor(vA, 2, 16);
      vA += __shfl_xor(vA, 4, 16);
      vA += __shfl_xor(vA, 8, 16);
      vB += __shfl_xor(vB, 1, 16);
      vB += __shfl_xor(vB, 2, 16);
      vB += __shfl_xor(vB, 4, 16);
      vB += __shfl_xor(vB, 8, 16);
      if (lrow == 0) {
        rowPart[(size_t)(i0 + kh * 4 + r) * NP + q] = vA;
        rowPart[(size_t)(i0 + 16 + kh * 4 + r) * NP + q] = vB;
      }
    }

    // Col-sums -> rowPart[q-rows][p] (p!=q; block-uniform branch)
    if (p != q) {
#pragma unroll
      for (int t = 0; t < 2; ++t)
#pragma unroll
        for (int nf = 0; nf < 4; ++nf) {
          float c = colAcc[t][nf];
          c += __shfl_xor(c, 16, 64);
          c += __shfl_xor(c, 32, 64);
          if (kh == 0) L.s.colRed[wave][t * 64 + nf * 16 + lrow] = c;
        }
      __syncthreads();
      if (tid < 128) {
        float s = (L.s.colRed[0][tid] + L.s.colRed[1][tid]) +
                  (L.s.colRed[2][tid] + L.s.colRed[3][tid]);
        rowPart[(size_t)(q0 + tid) * NP + p] = s;
      }
    }
    __syncthreads();   // Bs/colRed reads done before next stage
  }

  grid_barrier(&bars[1], tid);

  // ===== Phase 3: finalize (blocks 0..63), last block writes scalar =====
  if (bid >= 64) return;

  float logAcc = 0.f;
  if (tid < 128) {
    const int row = bid * 128 + tid;
    const float4* rp = reinterpret_cast<const float4*>(rowPart + (size_t)row * NP);
    float s = 0.f;
#pragma unroll
    for (int c = 0; c < NP / 4; ++c) {
      float4 v = rp[c];
      s += (v.x + v.y) + (v.z + v.w);
    }
    logAcc = logf(s - EXP10);
  }
  float cross = 0.f;
  if (tid < 64) {
    const int u = bid * 64 + tid;
    const unsigned* r0 = reinterpret_cast<const unsigned*>(Gb + (size_t)u * CDIM);
    const unsigned* r1 =
        reinterpret_cast<const unsigned*>(Gb + (size_t)(u + NLOC) * CDIM);
#pragma unroll
    for (int c = 0; c < 32; ++c) {
      unsigned a = r0[c], bb = r1[c];
      cross += bf2f(a & 0xffffu) * bf2f(bb & 0xffffu) + bf2f(a >> 16) * bf2f(bb >> 16);
    }
  }
  L.f.sA[tid] = logAcc;
  L.f.sB[tid] = cross;
  __syncthreads();
  for (int s = 128; s > 0; s >>= 1) {
    if (tid < s) { L.f.sA[tid] += L.f.sA[tid + s]; L.f.sB[tid] += L.f.sB[tid + s]; }
    __syncthreads();
  }
  if (tid == 0) {
    __hip_atomic_store(&partA[bid], L.f.sA[0], __ATOMIC_RELAXED, __HIP_MEMORY_SCOPE_AGENT);
    __hip_atomic_store(&partB[bid], L.f.sB[0], __ATOMIC_RELAXED, __HIP_MEMORY_SCOPE_AGENT);
    __threadfence();
    unsigned old = atomicAdd(&bars[2], 1u);
    L.f.lastFlag = (old == 63u) ? 1 : 0;
  }
  __syncthreads();

  if (L.f.lastFlag && tid < 64) {
    float a = __hip_atomic_load(&partA[tid], __ATOMIC_RELAXED, __HIP_MEMORY_SCOPE_AGENT);
    float c = __hip_atomic_load(&partB[tid], __ATOMIC_RELAXED, __HIP_MEMORY_SCOPE_AGENT);
#pragma unroll
    for (int s = 1; s < 64; s <<= 1) {
      a += __shfl_xor(a, s, 64);
      c += __shfl_xor(c, s, 64);
    }
    if (tid == 0) out[0] = (a - 2.0f * TINV * c) / (float)NROW;
  }
}

// ---------------------------------------------------------------------------
extern "C" void kernel_launch(void* const* d_in, const int* in_sizes, int n_in,
                              void* d_out, int out_size, void* d_ws, size_t ws_size,
                              hipStream_t stream) {
  const float* emb0 = (const float*)d_in[0];
  const float* emb1 = (const float*)d_in[1];
  const float* loc0 = (const float*)d_in[2];
  const float* loc1 = (const float*)d_in[3];
  float* out = (float*)d_out;
  char* ws = (char*)d_ws;

  // Layout: Gb 1MB | rowPart 2MB | partA 256B | partB 256B | bars
  u16* Gb           = (u16*)ws;
  float* rowPart    = (float*)(ws + (1ull << 20));
  float* partA      = (float*)(ws + (3ull << 20));
  float* partB      = (float*)(ws + (3ull << 20) + 256);
  unsigned* bars    = (unsigned*)(ws + (3ull << 20) + 512);

  hipMemsetAsync(bars, 0, 256, stream);   // zero barrier + finalize counters
  mega_kernel<<<NBLK, 256, 0, stream>>>(emb0, emb1, loc0, loc1, Gb, rowPart,
                                        partA, partB, bars, out);
}

// Round 10
// 141.487 us; speedup vs baseline: 2.3914x; 2.3914x over previous
//
#include <hip/hip_runtime.h>
#include <math.h>

// Problem constants (B=1, C=64, H=W=256, N=4096, T=0.1)
#define HW2     65536
#define NLOC    4096
#define NROW    8192
#define CDIM    64
#define TINV    10.0f
#define EXP10   22026.465794806718f   // exp(1/T)
#define NP      64                    // 128-row panels
#define NPAIR   2080                  // NP*(NP+1)/2

#if __has_builtin(__builtin_amdgcn_exp2f)
#define ASCALE  14.426950408889634f   // 10 * log2(e)
#define EXPFN(x) __builtin_amdgcn_exp2f(x)
#else
#define ASCALE  10.0f
#define EXPFN(x) __expf(x)
#endif

typedef __attribute__((ext_vector_type(8))) short bf16x8;
typedef __attribute__((ext_vector_type(4))) float f32x4;
typedef unsigned short u16;

__device__ __forceinline__ unsigned short f2bf(float f) {
  unsigned u = __builtin_bit_cast(unsigned, f);
  u += 0x7FFFu + ((u >> 16) & 1u);   // RNE
  return (unsigned short)(u >> 16);
}
__device__ __forceinline__ float bf2f(unsigned u16v) {
  unsigned u = u16v << 16;
  return __builtin_bit_cast(float, u);
}
// Scale a bf16x8 fragment by ASCALE with RNE re-round (bit-identical to the
// old Ga materialization; validated R9).
__device__ __forceinline__ bf16x8 scale8(bf16x8 r) {
  bf16x8 o;
#pragma unroll
  for (int j = 0; j < 8; ++j)
    o[j] = (short)f2bf(bf2f((unsigned short)r[j]) * ASCALE);
  return o;
}

// ---------------------------------------------------------------------------
// Kernel GC (channel-major gather): block = 32 gather-rows x 16 channels.
// 1024 blocks (4/CU) for gather MLP.  Writes Gb only (A-scale is in-register
// in simsum).  Wave lanes read scattered positions within 1-2 channel slabs.
// ---------------------------------------------------------------------------
__global__ __launch_bounds__(256) void gatherc_kernel(
    const float* __restrict__ emb0, const float* __restrict__ emb1,
    const float* __restrict__ loc0, const float* __restrict__ loc1,
    u16* __restrict__ Gb) {
  __shared__ int ind[32];
  __shared__ u16 Gs[32][18];          // pad 18: row stride 9 banks

  const int tid   = threadIdx.x;
  const int chunk = blockIdx.x;       // 0..255 -> rows chunk*32..+32
  const int cg    = blockIdx.y;       // 0..3   -> channels cg*16..+16
  const int eb    = chunk >> 7;
  const float* emb = eb ? emb1 : emb0;
  const float* loc = eb ? loc1 : loc0;

  if (tid < 32) {
    const int u = (chunk & 127) * 32 + tid;
    float2 lv = *reinterpret_cast<const float2*>(&loc[u * 2]);
    ind[tid] = (int)floorf(lv.x) * 256 + (int)floorf(lv.y);
  }
  __syncthreads();

  const int row = tid & 31;
  const int cs  = tid >> 5;           // 0..7
  const int pos = ind[row];
  float v0 = emb[(size_t)(cg * 16 + cs) * HW2 + pos];
  float v1 = emb[(size_t)(cg * 16 + cs + 8) * HW2 + pos];
  Gs[row][cs]     = f2bf(v0);
  Gs[row][cs + 8] = f2bf(v1);
  __syncthreads();

  if (tid < 64) {
    const int r = tid >> 1, h = tid & 1;
    bf16x8 v = *reinterpret_cast<const bf16x8*>(&Gs[r][h * 8]);
    *reinterpret_cast<bf16x8*>(
        &Gb[(size_t)(chunk * 32 + r) * CDIM + cg * 16 + h * 8]) = v;
  }
}

// ---------------------------------------------------------------------------
// Staging: one 64-row x 128B tile, XOR seg-swizzle (measured 0 conflicts).
// ---------------------------------------------------------------------------
__device__ __forceinline__ void stage_tile(u16* Bs, const u16* __restrict__ Gb,
                                           int jb, int buf, int tid, int wave,
                                           int srow, int ssl) {
#pragma unroll
  for (int r = 0; r < 2; ++r) {
    const u16* src = Gb + (size_t)(jb + r * 32 + srow) * CDIM + ssl * 8;
#if __has_builtin(__builtin_amdgcn_global_load_lds)
    u16* dst = Bs + buf * 4096 + r * 2048 + wave * 512;
    __builtin_amdgcn_global_load_lds(
        (const __attribute__((address_space(1))) unsigned int*)src,
        (__attribute__((address_space(3))) unsigned int*)dst, 16, 0, 0);
#else
    bf16x8 tmp = *reinterpret_cast<const bf16x8*>(src);
    *reinterpret_cast<bf16x8*>(Bs + buf * 4096 + r * 2048 + tid * 8) = tmp;
#endif
  }
}

// ---------------------------------------------------------------------------
// Kernel S (triangular + fused finalize): block b -> panel pair (p,q), p<=q.
// Row-sums -> rowPart[p-rows][q]; col-sums -> rowPart[q-rows][p] (p!=q).
// Band tiles (q==p+32) also compute the f32 cross dot for their 128 u's.
// Completion: fence + atomicAdd(panelCnt[p]) [+q]; 64th arrival finalizes
// the panel (sum 64 slots + log per row -> panelLog[x]); 64th panel bumps
// master and writes the scalar.  Counters spread: one 64B line per panel.
// ---------------------------------------------------------------------------
__global__ __launch_bounds__(256) void simsum_tri_kernel(
    const u16* __restrict__ Gb, float* __restrict__ rowPart,
    float* __restrict__ panelLog, float* __restrict__ bandPart,
    unsigned* __restrict__ bars, float* __restrict__ out) {
  __shared__ u16 Bs[2 * 64 * CDIM];    // 16 KB
  __shared__ float colRed[4][128];     // 2 KB
  __shared__ float red[256];           // 1 KB (reductions)
  __shared__ int sFinP, sFinQ, sMfin;

  const int tid  = threadIdx.x;
  const int lane = tid & 63;
  const int wave = tid >> 6;
  const int lrow = lane & 15;
  const int kh   = lane >> 4;

  const int b = blockIdx.x;
  int p = (int)((129.0f - sqrtf(16641.0f - 8.0f * (float)b)) * 0.5f);
  if (p < 0) p = 0;
  if (p > NP - 1) p = NP - 1;
#pragma unroll
  for (int it = 0; it < 3; ++it) {
    if (p > 0 && (p * NP - p * (p - 1) / 2) > b) --p;
    else if (((p + 1) * NP - (p + 1) * p / 2) <= b) ++p;
  }
  const int q  = p + (b - (p * NP - p * (p - 1) / 2));
  const int p0 = p * 128, q0 = q * 128;
  const int i0 = p0 + wave * 32;

  // A fragments from Gb, scaled in-register.
  const bf16x8* arowA =
      reinterpret_cast<const bf16x8*>(Gb + (size_t)(i0 + lrow) * CDIM + kh * 8);
  const bf16x8* arowB = reinterpret_cast<const bf16x8*>(
      Gb + (size_t)(i0 + 16 + lrow) * CDIM + kh * 8);
  bf16x8 aA0 = scale8(arowA[0]), aA1 = scale8(arowA[4]);
  bf16x8 aB0 = scale8(arowB[0]), aB1 = scale8(arowB[4]);

  const int srow = tid >> 3;
  const int ssl  = (tid & 7) ^ (srow & 7);
  stage_tile(Bs, Gb, q0,      0, tid, wave, srow, ssl);
  stage_tile(Bs, Gb, q0 + 64, 1, tid, wave, srow, ssl);
  __syncthreads();

  const int sp0 = ((kh ^ (lrow & 7)) << 3);
  const int sp1 = (((4 + kh) ^ (lrow & 7)) << 3);

  float accA[4][4], accB[4][4];
#pragma unroll
  for (int nf = 0; nf < 4; ++nf)
#pragma unroll
    for (int r = 0; r < 4; ++r) { accA[nf][r] = 0.f; accB[nf][r] = 0.f; }
  float colAcc[2][4];

#pragma unroll
  for (int t = 0; t < 2; ++t) {
    const u16* bs = Bs + t * 4096;
#pragma unroll
    for (int nf = 0; nf < 4; ++nf) {
      const int rb = (nf * 16 + lrow) * CDIM;
      bf16x8 b0 = *reinterpret_cast<const bf16x8*>(bs + rb + sp0);
      bf16x8 b1 = *reinterpret_cast<const bf16x8*>(bs + rb + sp1);
      f32x4 z = {0.f, 0.f, 0.f, 0.f};
      f32x4 tA = __builtin_amdgcn_mfma_f32_16x16x32_bf16(aA0, b0, z, 0, 0, 0);
      tA = __builtin_amdgcn_mfma_f32_16x16x32_bf16(aA1, b1, tA, 0, 0, 0);
      f32x4 tB = __builtin_amdgcn_mfma_f32_16x16x32_bf16(aB0, b0, z, 0, 0, 0);
      tB = __builtin_amdgcn_mfma_f32_16x16x32_bf16(aB1, b1, tB, 0, 0, 0);
      float cp = 0.f;
#pragma unroll
      for (int r = 0; r < 4; ++r) {
        float eA = EXPFN(tA[r]);
        float eB = EXPFN(tB[r]);
        accA[nf][r] += eA;
        accB[nf][r] += eB;
        cp += eA + eB;
      }
      colAcc[t][nf] = cp;
    }
  }

  // Row-sums -> rowPart[p-rows][q]
#pragma unroll
  for (int r = 0; r < 4; ++r) {
    float vA = (accA[0][r] + accA[1][r]) + (accA[2][r] + accA[3][r]);
    float vB = (accB[0][r] + accB[1][r]) + (accB[2][r] + accB[3][r]);
    vA += __shfl_xor(vA, 1, 16);
    vA += __shfl_xor(vA, 2, 16);
    vA += __shfl_xor(vA, 4, 16);
    vA += __shfl_xor(vA, 8, 16);
    vB += __shfl_xor(vB, 1, 16);
    vB += __shfl_xor(vB, 2, 16);
    vB += __shfl_xor(vB, 4, 16);
    vB += __shfl_xor(vB, 8, 16);
    if (lrow == 0) {
      rowPart[(size_t)(i0 + kh * 4 + r) * NP + q] = vA;
      rowPart[(size_t)(i0 + 16 + kh * 4 + r) * NP + q] = vB;
    }
  }

  // Col-sums -> rowPart[q-rows][p] (p!=q; block-uniform branch)
  if (p != q) {
#pragma unroll
    for (int t = 0; t < 2; ++t)
#pragma unroll
      for (int nf = 0; nf < 4; ++nf) {
        float c = colAcc[t][nf];
        c += __shfl_xor(c, 16, 64);
        c += __shfl_xor(c, 32, 64);
        if (kh == 0) colRed[wave][t * 64 + nf * 16 + lrow] = c;
      }
    __syncthreads();
    if (tid < 128) {
      float s = (colRed[0][tid] + colRed[1][tid]) +
                (colRed[2][tid] + colRed[3][tid]);
      rowPart[(size_t)(q0 + tid) * NP + p] = s;
    }
  }

  // Band cross-term (q == p+32): f32 dot(Gb[u], Gb[u+NLOC]) for this panel's
  // 128 u's -> bandPart[p].  Same numerics as the old finpart cross.
  if (q == p + 32) {
    float cr = 0.f;
    if (tid < 128) {
      const int u = p0 + tid;
      const unsigned* r0 = reinterpret_cast<const unsigned*>(Gb + (size_t)u * CDIM);
      const unsigned* r1 =
          reinterpret_cast<const unsigned*>(Gb + (size_t)(u + NLOC) * CDIM);
#pragma unroll
      for (int c = 0; c < 32; ++c) {
        unsigned a = r0[c], bb = r1[c];
        cr += bf2f(a & 0xffffu) * bf2f(bb & 0xffffu) +
              bf2f(a >> 16) * bf2f(bb >> 16);
      }
    }
    __syncthreads();
    red[tid] = cr;
    __syncthreads();
    for (int s = 128; s > 0; s >>= 1) {
      if (tid < s) red[tid] += red[tid + s];
      __syncthreads();
    }
    if (tid == 0) bandPart[p] = red[0];
  }

  // ---- completion counters (spread lines: panelCnt[x] = bars[x*16]) ----
  __syncthreads();
  if (tid == 0) {
    __threadfence();                           // release rowPart/bandPart
    unsigned oldP = atomicAdd(&bars[p * 16], 1u);
    sFinP = (oldP == 63u);
    int fq = 0;
    if (p != q) {
      unsigned oldQ = atomicAdd(&bars[q * 16], 1u);
      fq = (oldQ == 63u);
    }
    sFinQ = fq;
  }
  __syncthreads();

  // ---- panel finalize (rare: one block per panel) ----
#pragma unroll
  for (int e = 0; e < 2; ++e) {
    const int fin = e ? sFinQ : sFinP;
    const int x   = e ? q : p;
    if (!fin) continue;                        // block-uniform
    __threadfence();                           // acquire panel x's rowPart
    float logAcc = 0.f;
    if (tid < 128) {
      const int row = x * 128 + tid;
      const float4* rp =
          reinterpret_cast<const float4*>(rowPart + (size_t)row * NP);
      float s = 0.f;
#pragma unroll
      for (int c = 0; c < NP / 4; ++c) {
        float4 v = rp[c];
        s += (v.x + v.y) + (v.z + v.w);
      }
      logAcc = logf(s - EXP10);
    }
    red[tid] = logAcc;
    __syncthreads();
    for (int s = 128; s > 0; s >>= 1) {
      if (tid < s) red[tid] += red[tid + s];
      __syncthreads();
    }
    if (tid == 0) {
      panelLog[x] = red[0];
      __threadfence();                         // release panelLog
      unsigned om = atomicAdd(&bars[NP * 16], 1u);
      sMfin = (om == 63u);
    }
    __syncthreads();
    if (sMfin) {
      __threadfence();                         // acquire all panelLog/bandPart
      if (tid < 64) {
        float a = panelLog[tid];
        float c = (tid < 32) ? bandPart[tid] : 0.f;
#pragma unroll
        for (int s = 1; s < 64; s <<= 1) {
          a += __shfl_xor(a, s, 64);
          c += __shfl_xor(c, s, 64);
        }
        if (tid == 0) out[0] = (a - 2.0f * TINV * c) / (float)NROW;
      }
    }
    __syncthreads();
  }
}

// ---------------------------------------------------------------------------
extern "C" void kernel_launch(void* const* d_in, const int* in_sizes, int n_in,
                              void* d_out, int out_size, void* d_ws, size_t ws_size,
                              hipStream_t stream) {
  const float* emb0 = (const float*)d_in[0];
  const float* emb1 = (const float*)d_in[1];
  const float* loc0 = (const float*)d_in[2];
  const float* loc1 = (const float*)d_in[3];
  float* out = (float*)d_out;
  char* ws = (char*)d_ws;

  // Layout: Gb 1MB | rowPart 2MB | panelLog 256B | bandPart 128B | bars 8KB
  u16* Gb           = (u16*)ws;
  float* rowPart    = (float*)(ws + (1ull << 20));
  float* panelLog   = (float*)(ws + (3ull << 20));
  float* bandPart   = (float*)(ws + (3ull << 20) + 256);
  unsigned* bars    = (unsigned*)(ws + (3ull << 20) + 4096);

  hipMemsetAsync(bars, 0, 8192, stream);   // panel counters + master

  dim3 gg(256, 4);
  gatherc_kernel<<<gg, 256, 0, stream>>>(emb0, emb1, loc0, loc1, Gb);
  simsum_tri_kernel<<<NPAIR, 256, 0, stream>>>(Gb, rowPart, panelLog, bandPart,
                                               bars, out);
}

// Round 11
// 40.289 us; speedup vs baseline: 8.3979x; 3.5118x over previous
//
#include <hip/hip_runtime.h>
#include <math.h>

// Problem constants (B=1, C=64, H=W=256, N=4096, T=0.1)
#define HW2     65536
#define NLOC    4096
#define NROW    8192
#define CDIM    64
#define TINV    10.0f
#define EXP10   22026.465794806718f   // exp(1/T)
#define NP      64                    // 128-row panels
#define NPAIR   2080                  // NP*(NP+1)/2

#if __has_builtin(__builtin_amdgcn_exp2f)
#define ASCALE  14.426950408889634f   // 10 * log2(e)
#define EXPFN(x) __builtin_amdgcn_exp2f(x)
#else
#define ASCALE  10.0f
#define EXPFN(x) __expf(x)
#endif

typedef __attribute__((ext_vector_type(8))) short bf16x8;
typedef __attribute__((ext_vector_type(4))) float f32x4;
typedef unsigned short u16;

__device__ __forceinline__ unsigned short f2bf(float f) {
  unsigned u = __builtin_bit_cast(unsigned, f);
  u += 0x7FFFu + ((u >> 16) & 1u);   // RNE
  return (unsigned short)(u >> 16);
}
__device__ __forceinline__ float bf2f(unsigned u16v) {
  unsigned u = u16v << 16;
  return __builtin_bit_cast(float, u);
}
// Scale a bf16x8 fragment by ASCALE with RNE re-round (bit-identical to a
// materialized Ga; validated R9/R10, absmax 0).
__device__ __forceinline__ bf16x8 scale8(bf16x8 r) {
  bf16x8 o;
#pragma unroll
  for (int j = 0; j < 8; ++j)
    o[j] = (short)f2bf(bf2f((unsigned short)r[j]) * ASCALE);
  return o;
}

// ---------------------------------------------------------------------------
// Kernel GC (channel-major gather): 1024 blocks, 1D grid with XCD-aware
// decode: cg = bid&3, chunk = bid>>2.  Under round-robin bid->XCD dispatch,
// each XCD reads only one 16-channel slab group (8 MB) -> no cross-XCD L2
// duplication.  (Heuristic only; correctness independent of mapping.)
// Block = 32 gather-rows x 16 channels; writes Gb only.
// ---------------------------------------------------------------------------
__global__ __launch_bounds__(256) void gatherc_kernel(
    const float* __restrict__ emb0, const float* __restrict__ emb1,
    const float* __restrict__ loc0, const float* __restrict__ loc1,
    u16* __restrict__ Gb) {
  __shared__ int ind[32];
  __shared__ u16 Gs[32][18];          // pad 18: row stride 9 banks

  const int tid   = threadIdx.x;
  const int bid   = blockIdx.x;
  const int cg    = bid & 3;          // channels cg*16..+16 (XCD-pinned)
  const int chunk = bid >> 2;         // 0..255 -> rows chunk*32..+32
  const int eb    = chunk >> 7;
  const float* emb = eb ? emb1 : emb0;
  const float* loc = eb ? loc1 : loc0;

  if (tid < 32) {
    const int u = (chunk & 127) * 32 + tid;
    float2 lv = *reinterpret_cast<const float2*>(&loc[u * 2]);
    ind[tid] = (int)floorf(lv.x) * 256 + (int)floorf(lv.y);
  }
  __syncthreads();

  const int row = tid & 31;
  const int cs  = tid >> 5;           // 0..7
  const int pos = ind[row];
  float v0 = emb[(size_t)(cg * 16 + cs) * HW2 + pos];
  float v1 = emb[(size_t)(cg * 16 + cs + 8) * HW2 + pos];
  Gs[row][cs]     = f2bf(v0);
  Gs[row][cs + 8] = f2bf(v1);
  __syncthreads();

  if (tid < 64) {
    const int r = tid >> 1, h = tid & 1;
    bf16x8 v = *reinterpret_cast<const bf16x8*>(&Gs[r][h * 8]);
    *reinterpret_cast<bf16x8*>(
        &Gb[(size_t)(chunk * 32 + r) * CDIM + cg * 16 + h * 8]) = v;
  }
}

// ---------------------------------------------------------------------------
// Staging: one 64-row x 128B tile, XOR seg-swizzle (measured 0 conflicts).
// ---------------------------------------------------------------------------
__device__ __forceinline__ void stage_tile(u16* Bs, const u16* __restrict__ Gb,
                                           int jb, int buf, int tid, int wave,
                                           int srow, int ssl) {
#pragma unroll
  for (int r = 0; r < 2; ++r) {
    const u16* src = Gb + (size_t)(jb + r * 32 + srow) * CDIM + ssl * 8;
#if __has_builtin(__builtin_amdgcn_global_load_lds)
    u16* dst = Bs + buf * 4096 + r * 2048 + wave * 512;
    __builtin_amdgcn_global_load_lds(
        (const __attribute__((address_space(1))) unsigned int*)src,
        (__attribute__((address_space(3))) unsigned int*)dst, 16, 0, 0);
#else
    bf16x8 tmp = *reinterpret_cast<const bf16x8*>(src);
    *reinterpret_cast<bf16x8*>(Bs + buf * 4096 + r * 2048 + tid * 8) = tmp;
#endif
  }
}

// ---------------------------------------------------------------------------
// Kernel S (triangular): block b -> panel pair (p,q), p<=q, 128x128 tile.
// Row-sums -> rowPart[p-rows][q]; col-sums -> rowPart[q-rows][p] (p!=q).
// A-fragments scaled in-register (no Ga buffer).
// ---------------------------------------------------------------------------
__global__ __launch_bounds__(256) void simsum_tri_kernel(
    const u16* __restrict__ Gb, float* __restrict__ rowPart) {
  __shared__ u16 Bs[2 * 64 * CDIM];    // 16 KB
  __shared__ float colRed[4][128];     // 2 KB

  const int tid  = threadIdx.x;
  const int lane = tid & 63;
  const int wave = tid >> 6;
  const int lrow = lane & 15;
  const int kh   = lane >> 4;

  const int b = blockIdx.x;
  int p = (int)((129.0f - sqrtf(16641.0f - 8.0f * (float)b)) * 0.5f);
  if (p < 0) p = 0;
  if (p > NP - 1) p = NP - 1;
#pragma unroll
  for (int it = 0; it < 3; ++it) {
    if (p > 0 && (p * NP - p * (p - 1) / 2) > b) --p;
    else if (((p + 1) * NP - (p + 1) * p / 2) <= b) ++p;
  }
  const int q  = p + (b - (p * NP - p * (p - 1) / 2));
  const int p0 = p * 128, q0 = q * 128;
  const int i0 = p0 + wave * 32;

  const bf16x8* arowA =
      reinterpret_cast<const bf16x8*>(Gb + (size_t)(i0 + lrow) * CDIM + kh * 8);
  const bf16x8* arowB = reinterpret_cast<const bf16x8*>(
      Gb + (size_t)(i0 + 16 + lrow) * CDIM + kh * 8);
  bf16x8 aA0 = scale8(arowA[0]), aA1 = scale8(arowA[4]);
  bf16x8 aB0 = scale8(arowB[0]), aB1 = scale8(arowB[4]);

  const int srow = tid >> 3;
  const int ssl  = (tid & 7) ^ (srow & 7);
  stage_tile(Bs, Gb, q0,      0, tid, wave, srow, ssl);
  stage_tile(Bs, Gb, q0 + 64, 1, tid, wave, srow, ssl);
  __syncthreads();

  const int sp0 = ((kh ^ (lrow & 7)) << 3);
  const int sp1 = (((4 + kh) ^ (lrow & 7)) << 3);

  float accA[4][4], accB[4][4];
#pragma unroll
  for (int nf = 0; nf < 4; ++nf)
#pragma unroll
    for (int r = 0; r < 4; ++r) { accA[nf][r] = 0.f; accB[nf][r] = 0.f; }
  float colAcc[2][4];

#pragma unroll
  for (int t = 0; t < 2; ++t) {
    const u16* bs = Bs + t * 4096;
#pragma unroll
    for (int nf = 0; nf < 4; ++nf) {
      const int rb = (nf * 16 + lrow) * CDIM;
      bf16x8 b0 = *reinterpret_cast<const bf16x8*>(bs + rb + sp0);
      bf16x8 b1 = *reinterpret_cast<const bf16x8*>(bs + rb + sp1);
      f32x4 z = {0.f, 0.f, 0.f, 0.f};
      f32x4 tA = __builtin_amdgcn_mfma_f32_16x16x32_bf16(aA0, b0, z, 0, 0, 0);
      tA = __builtin_amdgcn_mfma_f32_16x16x32_bf16(aA1, b1, tA, 0, 0, 0);
      f32x4 tB = __builtin_amdgcn_mfma_f32_16x16x32_bf16(aB0, b0, z, 0, 0, 0);
      tB = __builtin_amdgcn_mfma_f32_16x16x32_bf16(aB1, b1, tB, 0, 0, 0);
      float cp = 0.f;
#pragma unroll
      for (int r = 0; r < 4; ++r) {
        float eA = EXPFN(tA[r]);
        float eB = EXPFN(tB[r]);
        accA[nf][r] += eA;
        accB[nf][r] += eB;
        cp += eA + eB;
      }
      colAcc[t][nf] = cp;
    }
  }

#pragma unroll
  for (int r = 0; r < 4; ++r) {
    float vA = (accA[0][r] + accA[1][r]) + (accA[2][r] + accA[3][r]);
    float vB = (accB[0][r] + accB[1][r]) + (accB[2][r] + accB[3][r]);
    vA += __shfl_xor(vA, 1, 16);
    vA += __shfl_xor(vA, 2, 16);
    vA += __shfl_xor(vA, 4, 16);
    vA += __shfl_xor(vA, 8, 16);
    vB += __shfl_xor(vB, 1, 16);
    vB += __shfl_xor(vB, 2, 16);
    vB += __shfl_xor(vB, 4, 16);
    vB += __shfl_xor(vB, 8, 16);
    if (lrow == 0) {
      rowPart[(size_t)(i0 + kh * 4 + r) * NP + q] = vA;
      rowPart[(size_t)(i0 + 16 + kh * 4 + r) * NP + q] = vB;
    }
  }

  if (p != q) {
#pragma unroll
    for (int t = 0; t < 2; ++t)
#pragma unroll
      for (int nf = 0; nf < 4; ++nf) {
        float c = colAcc[t][nf];
        c += __shfl_xor(c, 16, 64);
        c += __shfl_xor(c, 32, 64);
        if (kh == 0) colRed[wave][t * 64 + nf * 16 + lrow] = c;
      }
    __syncthreads();                  // p!=q is block-uniform -> legal
    if (tid < 128) {
      float s = (colRed[0][tid] + colRed[1][tid]) +
                (colRed[2][tid] + colRed[3][tid]);
      rowPart[(size_t)(q0 + tid) * NP + p] = s;
    }
  }
}

// ---------------------------------------------------------------------------
// Kernel F (fused): per-block partials; last block (device-scope counter,
// 64 RMWs on one line — proven scale) reduces in fixed order, writes scalar.
// ---------------------------------------------------------------------------
__global__ __launch_bounds__(256) void finpart_kernel(
    const u16* __restrict__ Gb, const float* __restrict__ rowPart,
    float* __restrict__ partA, float* __restrict__ partB,
    unsigned* __restrict__ counter, float* __restrict__ out) {
  __shared__ float sA[256];
  __shared__ float sB[256];
  __shared__ int lastFlag;
  const int tid = threadIdx.x, b = blockIdx.x;

  float logAcc = 0.f;
  if (tid < 128) {
    const int row = b * 128 + tid;
    const float4* rp = reinterpret_cast<const float4*>(rowPart + (size_t)row * NP);
    float s = 0.f;
#pragma unroll
    for (int c = 0; c < NP / 4; ++c) {
      float4 v = rp[c];
      s += (v.x + v.y) + (v.z + v.w);
    }
    logAcc = logf(s - EXP10);
  }
  float cross = 0.f;
  if (tid < 64) {
    const int u = b * 64 + tid;
    const unsigned* r0 = reinterpret_cast<const unsigned*>(Gb + (size_t)u * CDIM);
    const unsigned* r1 =
        reinterpret_cast<const unsigned*>(Gb + (size_t)(u + NLOC) * CDIM);
#pragma unroll
    for (int c = 0; c < 32; ++c) {
      unsigned a = r0[c], bb = r1[c];
      cross += bf2f(a & 0xffffu) * bf2f(bb & 0xffffu) + bf2f(a >> 16) * bf2f(bb >> 16);
    }
  }
  sA[tid] = logAcc;
  sB[tid] = cross;
  __syncthreads();
  for (int s = 128; s > 0; s >>= 1) {
    if (tid < s) { sA[tid] += sA[tid + s]; sB[tid] += sB[tid + s]; }
    __syncthreads();
  }
  if (tid == 0) {
    __hip_atomic_store(&partA[b], sA[0], __ATOMIC_RELAXED, __HIP_MEMORY_SCOPE_AGENT);
    __hip_atomic_store(&partB[b], sB[0], __ATOMIC_RELAXED, __HIP_MEMORY_SCOPE_AGENT);
    __threadfence();                          // release partials device-wide
    unsigned old = atomicAdd(counter, 1u);    // device-scope by default
    lastFlag = (old == 63u) ? 1 : 0;
  }
  __syncthreads();

  if (lastFlag && tid < 64) {
    float a = __hip_atomic_load(&partA[tid], __ATOMIC_RELAXED, __HIP_MEMORY_SCOPE_AGENT);
    float c = __hip_atomic_load(&partB[tid], __ATOMIC_RELAXED, __HIP_MEMORY_SCOPE_AGENT);
#pragma unroll
    for (int s = 1; s < 64; s <<= 1) {        // fixed-order butterfly
      a += __shfl_xor(a, s, 64);
      c += __shfl_xor(c, s, 64);
    }
    if (tid == 0) out[0] = (a - 2.0f * TINV * c) / (float)NROW;
  }
}

// ---------------------------------------------------------------------------
extern "C" void kernel_launch(void* const* d_in, const int* in_sizes, int n_in,
                              void* d_out, int out_size, void* d_ws, size_t ws_size,
                              hipStream_t stream) {
  const float* emb0 = (const float*)d_in[0];
  const float* emb1 = (const float*)d_in[1];
  const float* loc0 = (const float*)d_in[2];
  const float* loc1 = (const float*)d_in[3];
  float* out = (float*)d_out;
  char* ws = (char*)d_ws;

  // Layout: Gb 1MB | rowPart 2MB | partA 256B | partB 256B | counter
  u16* Gb           = (u16*)ws;
  float* rowPart    = (float*)(ws + (1ull << 20));
  float* partA      = (float*)(ws + (3ull << 20));
  float* partB      = (float*)(ws + (3ull << 20) + 256);
  unsigned* counter = (unsigned*)(ws + (3ull << 20) + 512);

  hipMemsetAsync(counter, 0, 64, stream);

  gatherc_kernel<<<1024, 256, 0, stream>>>(emb0, emb1, loc0, loc1, Gb);
  simsum_tri_kernel<<<NPAIR, 256, 0, stream>>>(Gb, rowPart);
  finpart_kernel<<<64, 256, 0, stream>>>(Gb, rowPart, partA, partB, counter, out);
}

// Round 12
// 37.280 us; speedup vs baseline: 9.0757x; 1.0807x over previous
//
#include <hip/hip_runtime.h>
#include <math.h>

// Problem constants (B=1, C=64, H=W=256, N=4096, T=0.1)
#define HW2     65536
#define NLOC    4096
#define NROW    8192
#define CDIM    64
#define TINV    10.0f
#define EXP10   22026.465794806718f   // exp(1/T)
#define NP      64                    // 128-row panels
#define NPAIR   2080                  // NP*(NP+1)/2

#if __has_builtin(__builtin_amdgcn_exp2f)
#define ASCALE  14.426950408889634f   // 10 * log2(e)
#define EXPFN(x) __builtin_amdgcn_exp2f(x)
#else
#define ASCALE  10.0f
#define EXPFN(x) __expf(x)
#endif

typedef __attribute__((ext_vector_type(8))) short bf16x8;
typedef __attribute__((ext_vector_type(4))) float f32x4;
typedef unsigned short u16;

__device__ __forceinline__ unsigned short f2bf(float f) {
  unsigned u = __builtin_bit_cast(unsigned, f);
  u += 0x7FFFu + ((u >> 16) & 1u);   // RNE
  return (unsigned short)(u >> 16);
}
__device__ __forceinline__ float bf2f(unsigned u16v) {
  unsigned u = u16v << 16;
  return __builtin_bit_cast(float, u);
}
// Scale a bf16x8 fragment by ASCALE with RNE re-round (bit-identical to a
// materialized Ga; validated R9/R10/R11, absmax 0).
__device__ __forceinline__ bf16x8 scale8(bf16x8 r) {
  bf16x8 o;
#pragma unroll
  for (int j = 0; j < 8; ++j)
    o[j] = (short)f2bf(bf2f((unsigned short)r[j]) * ASCALE);
  return o;
}

// ---------------------------------------------------------------------------
// Kernel GC (channel-major gather) — R8-proven shape: block = 64 rows x 16
// channels, grid (128,4).  A wave's 64 lanes read 64 scattered positions
// within ONE 256-KB channel slab.  Writes Gb only.  Block (0,0) zeroes the
// finpart counter (kernel-boundary ordering guarantees visibility).
// ---------------------------------------------------------------------------
__global__ __launch_bounds__(256) void gatherc_kernel(
    const float* __restrict__ emb0, const float* __restrict__ emb1,
    const float* __restrict__ loc0, const float* __restrict__ loc1,
    u16* __restrict__ Gb, unsigned* __restrict__ counter) {
  __shared__ int ind[64];
  __shared__ u16 Gs[64][18];          // pad 18: row stride 9 banks, coprime 32

  const int tid   = threadIdx.x;
  const int chunk = blockIdx.x;       // 0..127 -> rows chunk*64..+64
  const int cg    = blockIdx.y;       // 0..3   -> channels cg*16..+16
  const int eb    = chunk >> 6;
  const float* emb = eb ? emb1 : emb0;
  const float* loc = eb ? loc1 : loc0;

  if (chunk == 0 && cg == 0 && tid == 0) *counter = 0u;

  if (tid < 64) {
    const int u = (chunk & 63) * 64 + tid;
    float2 lv = *reinterpret_cast<const float2*>(&loc[u * 2]);
    ind[tid] = (int)floorf(lv.x) * 256 + (int)floorf(lv.y);
  }
  __syncthreads();

  const int row = tid & 63;
  const int cq  = tid >> 6;           // 0..3
  const int pos = ind[row];
#pragma unroll
  for (int k = 0; k < 4; ++k) {
    const int cl = cq + 4 * k;        // 0..15, each (row,cl) exactly once
    float v = emb[(size_t)(cg * 16 + cl) * HW2 + pos];
    Gs[row][cl] = f2bf(v);
  }
  __syncthreads();

  if (tid < 128) {
    const int r2 = tid >> 1, h = tid & 1;
    bf16x8 v = *reinterpret_cast<const bf16x8*>(&Gs[r2][h * 8]);
    *reinterpret_cast<bf16x8*>(
        &Gb[(size_t)(chunk * 64 + r2) * CDIM + cg * 16 + h * 8]) = v;
  }
}

// ---------------------------------------------------------------------------
// Staging: one 64-row x 128B tile, XOR seg-swizzle (measured 0 conflicts).
// ---------------------------------------------------------------------------
__device__ __forceinline__ void stage_tile(u16* Bs, const u16* __restrict__ Gb,
                                           int jb, int buf, int tid, int wave,
                                           int srow, int ssl) {
#pragma unroll
  for (int r = 0; r < 2; ++r) {
    const u16* src = Gb + (size_t)(jb + r * 32 + srow) * CDIM + ssl * 8;
#if __has_builtin(__builtin_amdgcn_global_load_lds)
    u16* dst = Bs + buf * 4096 + r * 2048 + wave * 512;
    __builtin_amdgcn_global_load_lds(
        (const __attribute__((address_space(1))) unsigned int*)src,
        (__attribute__((address_space(3))) unsigned int*)dst, 16, 0, 0);
#else
    bf16x8 tmp = *reinterpret_cast<const bf16x8*>(src);
    *reinterpret_cast<bf16x8*>(Bs + buf * 4096 + r * 2048 + tid * 8) = tmp;
#endif
  }
}

// ---------------------------------------------------------------------------
// Kernel S (triangular): block b -> panel pair (p,q), p<=q, 128x128 tile.
// Row-sums -> rowPart[p-rows][q]; col-sums -> rowPart[q-rows][p] (p!=q).
// A-fragments scaled in-register (no Ga buffer).
// ---------------------------------------------------------------------------
__global__ __launch_bounds__(256) void simsum_tri_kernel(
    const u16* __restrict__ Gb, float* __restrict__ rowPart) {
  __shared__ u16 Bs[2 * 64 * CDIM];    // 16 KB
  __shared__ float colRed[4][128];     // 2 KB

  const int tid  = threadIdx.x;
  const int lane = tid & 63;
  const int wave = tid >> 6;
  const int lrow = lane & 15;
  const int kh   = lane >> 4;

  const int b = blockIdx.x;
  int p = (int)((129.0f - sqrtf(16641.0f - 8.0f * (float)b)) * 0.5f);
  if (p < 0) p = 0;
  if (p > NP - 1) p = NP - 1;
#pragma unroll
  for (int it = 0; it < 3; ++it) {
    if (p > 0 && (p * NP - p * (p - 1) / 2) > b) --p;
    else if (((p + 1) * NP - (p + 1) * p / 2) <= b) ++p;
  }
  const int q  = p + (b - (p * NP - p * (p - 1) / 2));
  const int p0 = p * 128, q0 = q * 128;
  const int i0 = p0 + wave * 32;

  const bf16x8* arowA =
      reinterpret_cast<const bf16x8*>(Gb + (size_t)(i0 + lrow) * CDIM + kh * 8);
  const bf16x8* arowB = reinterpret_cast<const bf16x8*>(
      Gb + (size_t)(i0 + 16 + lrow) * CDIM + kh * 8);
  bf16x8 aA0 = scale8(arowA[0]), aA1 = scale8(arowA[4]);
  bf16x8 aB0 = scale8(arowB[0]), aB1 = scale8(arowB[4]);

  const int srow = tid >> 3;
  const int ssl  = (tid & 7) ^ (srow & 7);
  stage_tile(Bs, Gb, q0,      0, tid, wave, srow, ssl);
  stage_tile(Bs, Gb, q0 + 64, 1, tid, wave, srow, ssl);
  __syncthreads();

  const int sp0 = ((kh ^ (lrow & 7)) << 3);
  const int sp1 = (((4 + kh) ^ (lrow & 7)) << 3);

  float accA[4][4], accB[4][4];
#pragma unroll
  for (int nf = 0; nf < 4; ++nf)
#pragma unroll
    for (int r = 0; r < 4; ++r) { accA[nf][r] = 0.f; accB[nf][r] = 0.f; }
  float colAcc[2][4];

#pragma unroll
  for (int t = 0; t < 2; ++t) {
    const u16* bs = Bs + t * 4096;
#pragma unroll
    for (int nf = 0; nf < 4; ++nf) {
      const int rb = (nf * 16 + lrow) * CDIM;
      bf16x8 b0 = *reinterpret_cast<const bf16x8*>(bs + rb + sp0);
      bf16x8 b1 = *reinterpret_cast<const bf16x8*>(bs + rb + sp1);
      f32x4 z = {0.f, 0.f, 0.f, 0.f};
      f32x4 tA = __builtin_amdgcn_mfma_f32_16x16x32_bf16(aA0, b0, z, 0, 0, 0);
      tA = __builtin_amdgcn_mfma_f32_16x16x32_bf16(aA1, b1, tA, 0, 0, 0);
      f32x4 tB = __builtin_amdgcn_mfma_f32_16x16x32_bf16(aB0, b0, z, 0, 0, 0);
      tB = __builtin_amdgcn_mfma_f32_16x16x32_bf16(aB1, b1, tB, 0, 0, 0);
      float cp = 0.f;
#pragma unroll
      for (int r = 0; r < 4; ++r) {
        float eA = EXPFN(tA[r]);
        float eB = EXPFN(tB[r]);
        accA[nf][r] += eA;
        accB[nf][r] += eB;
        cp += eA + eB;
      }
      colAcc[t][nf] = cp;
    }
  }

#pragma unroll
  for (int r = 0; r < 4; ++r) {
    float vA = (accA[0][r] + accA[1][r]) + (accA[2][r] + accA[3][r]);
    float vB = (accB[0][r] + accB[1][r]) + (accB[2][r] + accB[3][r]);
    vA += __shfl_xor(vA, 1, 16);
    vA += __shfl_xor(vA, 2, 16);
    vA += __shfl_xor(vA, 4, 16);
    vA += __shfl_xor(vA, 8, 16);
    vB += __shfl_xor(vB, 1, 16);
    vB += __shfl_xor(vB, 2, 16);
    vB += __shfl_xor(vB, 4, 16);
    vB += __shfl_xor(vB, 8, 16);
    if (lrow == 0) {
      rowPart[(size_t)(i0 + kh * 4 + r) * NP + q] = vA;
      rowPart[(size_t)(i0 + 16 + kh * 4 + r) * NP + q] = vB;
    }
  }

  if (p != q) {
#pragma unroll
    for (int t = 0; t < 2; ++t)
#pragma unroll
      for (int nf = 0; nf < 4; ++nf) {
        float c = colAcc[t][nf];
        c += __shfl_xor(c, 16, 64);
        c += __shfl_xor(c, 32, 64);
        if (kh == 0) colRed[wave][t * 64 + nf * 16 + lrow] = c;
      }
    __syncthreads();                  // p!=q is block-uniform -> legal
    if (tid < 128) {
      float s = (colRed[0][tid] + colRed[1][tid]) +
                (colRed[2][tid] + colRed[3][tid]);
      rowPart[(size_t)(q0 + tid) * NP + p] = s;
    }
  }
}

// ---------------------------------------------------------------------------
// Kernel F (fused): per-block partials; last block (device-scope counter,
// 64 RMWs on one line — proven scale) reduces in fixed order, writes scalar.
// ---------------------------------------------------------------------------
__global__ __launch_bounds__(256) void finpart_kernel(
    const u16* __restrict__ Gb, const float* __restrict__ rowPart,
    float* __restrict__ partA, float* __restrict__ partB,
    unsigned* __restrict__ counter, float* __restrict__ out) {
  __shared__ float sA[256];
  __shared__ float sB[256];
  __shared__ int lastFlag;
  const int tid = threadIdx.x, b = blockIdx.x;

  float logAcc = 0.f;
  if (tid < 128) {
    const int row = b * 128 + tid;
    const float4* rp = reinterpret_cast<const float4*>(rowPart + (size_t)row * NP);
    float s = 0.f;
#pragma unroll
    for (int c = 0; c < NP / 4; ++c) {
      float4 v = rp[c];
      s += (v.x + v.y) + (v.z + v.w);
    }
    logAcc = logf(s - EXP10);
  }
  float cross = 0.f;
  if (tid < 64) {
    const int u = b * 64 + tid;
    const unsigned* r0 = reinterpret_cast<const unsigned*>(Gb + (size_t)u * CDIM);
    const unsigned* r1 =
        reinterpret_cast<const unsigned*>(Gb + (size_t)(u + NLOC) * CDIM);
#pragma unroll
    for (int c = 0; c < 32; ++c) {
      unsigned a = r0[c], bb = r1[c];
      cross += bf2f(a & 0xffffu) * bf2f(bb & 0xffffu) + bf2f(a >> 16) * bf2f(bb >> 16);
    }
  }
  sA[tid] = logAcc;
  sB[tid] = cross;
  __syncthreads();
  for (int s = 128; s > 0; s >>= 1) {
    if (tid < s) { sA[tid] += sA[tid + s]; sB[tid] += sB[tid + s]; }
    __syncthreads();
  }
  if (tid == 0) {
    __hip_atomic_store(&partA[b], sA[0], __ATOMIC_RELAXED, __HIP_MEMORY_SCOPE_AGENT);
    __hip_atomic_store(&partB[b], sB[0], __ATOMIC_RELAXED, __HIP_MEMORY_SCOPE_AGENT);
    __threadfence();                          // release partials device-wide
    unsigned old = atomicAdd(counter, 1u);    // device-scope by default
    lastFlag = (old == 63u) ? 1 : 0;
  }
  __syncthreads();

  if (lastFlag && tid < 64) {
    float a = __hip_atomic_load(&partA[tid], __ATOMIC_RELAXED, __HIP_MEMORY_SCOPE_AGENT);
    float c = __hip_atomic_load(&partB[tid], __ATOMIC_RELAXED, __HIP_MEMORY_SCOPE_AGENT);
#pragma unroll
    for (int s = 1; s < 64; s <<= 1) {        // fixed-order butterfly
      a += __shfl_xor(a, s, 64);
      c += __shfl_xor(c, s, 64);
    }
    if (tid == 0) out[0] = (a - 2.0f * TINV * c) / (float)NROW;
  }
}

// ---------------------------------------------------------------------------
extern "C" void kernel_launch(void* const* d_in, const int* in_sizes, int n_in,
                              void* d_out, int out_size, void* d_ws, size_t ws_size,
                              hipStream_t stream) {
  const float* emb0 = (const float*)d_in[0];
  const float* emb1 = (const float*)d_in[1];
  const float* loc0 = (const float*)d_in[2];
  const float* loc1 = (const float*)d_in[3];
  float* out = (float*)d_out;
  char* ws = (char*)d_ws;

  // Layout: Gb 1MB | rowPart 2MB | partA 256B | partB 256B | counter
  u16* Gb           = (u16*)ws;
  float* rowPart    = (float*)(ws + (1ull << 20));
  float* partA      = (float*)(ws + (3ull << 20));
  float* partB      = (float*)(ws + (3ull << 20) + 256);
  unsigned* counter = (unsigned*)(ws + (3ull << 20) + 512);

  dim3 gg(128, 4);
  gatherc_kernel<<<gg, 256, 0, stream>>>(emb0, emb1, loc0, loc1, Gb, counter);
  simsum_tri_kernel<<<NPAIR, 256, 0, stream>>>(Gb, rowPart);
  finpart_kernel<<<64, 256, 0, stream>>>(Gb, rowPart, partA, partB, counter, out);
}